// Round 8
// baseline (731.818 us; speedup 1.0000x reference)
//
#include <hip/hip_runtime.h>

typedef _Float16 h8 __attribute__((ext_vector_type(8)));
typedef _Float16 h4 __attribute__((ext_vector_type(4)));
typedef float f4 __attribute__((ext_vector_type(4)));
typedef int i4v __attribute__((ext_vector_type(4)));

#define B_ 4096
#define T_ 64
#define I_ 8
#define H_ 128

// LDS layout (bytes). Total 149504 <= 163840.
#define WC0_OFF 0            // [512 packed-gates][128 k] fp16, XOR-swizzled = 131072
#define H0_OFF  131072       // 2 x [16 batch][128 u] fp16, swizzled        = 8192
#define H1_OFF  139264       // 2 x [16][128]                               = 8192
#define BB_OFF  147456       // [512] f32 L1 bias, packed order             = 2048
#define LDS_TOTAL 149504

#define LOG2E    1.4426950408889634f
#define TWOLOG2E 2.8853900817779268f

// gates arrive pre-scaled by log2e (i,f,o) / 2*log2e (g)
__device__ __forceinline__ float sigm2_(float v) {
    return __builtin_amdgcn_rcpf(1.f + exp2f(-v));
}
__device__ __forceinline__ float tanh2_(float v) {
    return 1.f - 2.f * __builtin_amdgcn_rcpf(exp2f(v) + 1.f);
}
__device__ __forceinline__ float tanhn_(float v) {   // natural units (for c)
    return 1.f - 2.f * __builtin_amdgcn_rcpf(exp2f(TWOLOG2E * v) + 1.f);
}
// packed gate row p = w*64 + j*16 + G4*4 + q  ->  original row gs = q*H + u,
// u = w*16 + G4*4 + j
__device__ __forceinline__ int gs_of(int p) {
    return (p & 3) * H_ + (p >> 6) * 16 + ((p >> 2) & 3) * 4 + ((p >> 4) & 3);
}
__device__ __forceinline__ float scl_(int q) { return (q == 2) ? TWOLOG2E : LOG2E; }

// ---- inline-asm MFMA (K=32 f16). acc forced to VGPR class; L1 weights come
// from AGPRs ("a" constraint) so the 128 idle accumulator registers hold Wc1 —
// the allocator memory-spilled anything above 128 arch VGPRs in rounds 3-7
// regardless of __launch_bounds__/waves_per_eu attributes.
__device__ __forceinline__ void mfma_v(f4& acc, const h8& a, const h8& b) {
    asm volatile("v_mfma_f32_16x16x32_f16 %0, %1, %2, %0"
                 : "+v"(acc) : "v"(a), "v"(b));
}
// first-in-chain: C was just VALU-zeroed -> 2+ wait states before MFMA reads it
__device__ __forceinline__ void mfma_v0(f4& acc, const h8& a, const h8& b) {
    asm volatile("s_nop 2\n\tv_mfma_f32_16x16x32_f16 %0, %1, %2, %0"
                 : "+v"(acc) : "v"(a), "v"(b));
}
__device__ __forceinline__ void mfma_a(f4& acc, const i4v& a, const h8& b) {
    asm volatile("v_mfma_f32_16x16x32_f16 %0, %1, %2, %0"
                 : "+v"(acc) : "a"(a), "v"(b));
}
// last-in-chain: next reader is VALU (epilogue); asm MFMA->VALU hazard is not
// compiler-tracked, so drain the XDL pipe here.
__device__ __forceinline__ void mfma_a_last(f4& acc, const i4v& a, const h8& b) {
    asm volatile("v_mfma_f32_16x16x32_f16 %0, %1, %2, %0\n\ts_nop 7\n\ts_nop 7"
                 : "+v"(acc) : "a"(a), "v"(b));
}

__global__ void lstm_fused_kernel(
    const float* __restrict__ x,
    const float* __restrict__ Wih0, const float* __restrict__ Whh0,
    const float* __restrict__ bih0, const float* __restrict__ bhh0,
    const float* __restrict__ Wih1, const float* __restrict__ Whh1,
    const float* __restrict__ bih1, const float* __restrict__ bhh1,
    const float* __restrict__ Wd1, const float* __restrict__ bd1,
    const float* __restrict__ Wd2, const float* __restrict__ bd2,
    float* __restrict__ out)
{
    __shared__ __align__(16) unsigned char lds[LDS_TOTAL];
    const int tid = threadIdx.x;
    const int w   = tid >> 6;
    const int l   = tid & 63;
    const int c16 = l & 15;
    const int G4  = l >> 4;
    const int rowbase = blockIdx.x * 16;
    const int swzl = (l & 7) << 4;

    // ---- init: Wc0 (packed order, prescaled, fp16, swizzled) -> LDS
    {
        const int p  = tid;
        const int gs = gs_of(p);
        const float sc = scl_(p & 3);
        const float* src = Whh0 + (size_t)gs * H_;
        const int swz = (p & 7) << 4;
        unsigned char* dst = lds + WC0_OFF + p * 256;
#pragma unroll
        for (int kb = 0; kb < 16; kb++) {
            float4 f0 = *(const float4*)(src + kb * 8);
            float4 f1 = *(const float4*)(src + kb * 8 + 4);
            h8 v;
            v[0]=(_Float16)(f0.x*sc); v[1]=(_Float16)(f0.y*sc);
            v[2]=(_Float16)(f0.z*sc); v[3]=(_Float16)(f0.w*sc);
            v[4]=(_Float16)(f1.x*sc); v[5]=(_Float16)(f1.y*sc);
            v[6]=(_Float16)(f1.z*sc); v[7]=(_Float16)(f1.w*sc);
            *(h8*)(dst + ((kb * 16) ^ swz)) = v;
        }
    }
    // zero the t=0 read buffers (index 1); L1 bias (packed) -> LDS
    {
        f4 z = {0.f, 0.f, 0.f, 0.f};
        if (tid < 256) *(f4*)(lds + H0_OFF + 4096 + tid * 16) = z;
        else           *(f4*)(lds + H1_OFF + 4096 + (tid - 256) * 16) = z;
        const int gs = gs_of(tid);
        ((float*)(lds + BB_OFF))[tid] = (bih1[gs] + bhh1[gs]) * scl_(tid & 3);
    }

    // ---- init: Wc1 A-frags -> AGPR bank; x-weight/bias frag (K=16), prescaled
    i4v wc1a[4][8];
    h4 ax16[4];
    {
        const float sc1 = scl_(c16 & 3);
#pragma unroll
        for (int j = 0; j < 4; j++) {
            const int gs = gs_of(w * 64 + j * 16 + c16);
#pragma unroll
            for (int ks = 0; ks < 8; ks++) {
                const int k0 = ks * 32 + G4 * 8;
                const float* src = (k0 < 128) ? (Whh1 + (size_t)gs * H_ + k0)
                                              : (Wih1 + (size_t)gs * H_ + (k0 - 128));
                float4 f0 = *(const float4*)src;
                float4 f1 = *(const float4*)(src + 4);
                h8 v;
                v[0]=(_Float16)(f0.x*sc1); v[1]=(_Float16)(f0.y*sc1);
                v[2]=(_Float16)(f0.z*sc1); v[3]=(_Float16)(f0.w*sc1);
                v[4]=(_Float16)(f1.x*sc1); v[5]=(_Float16)(f1.y*sc1);
                v[6]=(_Float16)(f1.z*sc1); v[7]=(_Float16)(f1.w*sc1);
                wc1a[j][ks] = *(i4v*)&v;
            }
            h4 a;
#pragma unroll
            for (int e = 0; e < 4; e++) {
                const int k = G4 * 4 + e;
                float val = 0.f;
                if (k < 8)       val = Wih0[(size_t)gs * I_ + k] * sc1;
                else if (k == 8) val = (bih0[gs] + bhh0[gs]) * sc1;
                a[e] = (_Float16)val;
            }
            ax16[j] = a;
        }
    }
    // pin the 32 Wc1 fragments (128 regs) into the AGPR class
#pragma unroll
    for (int j = 0; j < 4; j++)
#pragma unroll
        for (int ks = 0; ks < 8; ks++)
            asm volatile("" : "+a"(wc1a[j][ks]));

    const float* xrow = x + (size_t)(rowbase + c16) * T_ * I_;
    float4 xf0 = *(const float4*)(xrow);
    float4 xf1 = *(const float4*)(xrow + 4);

    float c0r[4] = {0.f, 0.f, 0.f, 0.f};
    float c1r[4] = {0.f, 0.f, 0.f, 0.f};

    __syncthreads();

    int cur = 0;
    for (int t = 0; t < T_; t++) {
        // B-frag (K=16) for the x/bias chunk: k<8 = x_t, k=8 -> 1.0
        h4 bx;
        bx[0] = (_Float16)0.f; bx[1] = (_Float16)0.f;
        bx[2] = (_Float16)0.f; bx[3] = (_Float16)0.f;
        if (G4 == 0) {
            bx[0]=(_Float16)xf0.x; bx[1]=(_Float16)xf0.y;
            bx[2]=(_Float16)xf0.z; bx[3]=(_Float16)xf0.w;
        } else if (G4 == 1) {
            bx[0]=(_Float16)xf1.x; bx[1]=(_Float16)xf1.y;
            bx[2]=(_Float16)xf1.z; bx[3]=(_Float16)xf1.w;
        } else if (G4 == 2) {
            bx[0] = (_Float16)1.f;
        }
        if (t < T_ - 1) {
            xf0 = *(const float4*)(xrow + (t + 1) * 8);
            xf1 = *(const float4*)(xrow + (t + 1) * 8 + 4);
        }

        // ---------------- layer 0 MFMAs (h0_old), Wc0 from LDS
        f4 acc0[4], acc1[4];
        {
            f4 z = {0.f, 0.f, 0.f, 0.f};
#pragma unroll
            for (int j = 0; j < 4; j++) acc0[j] = z;
        }
        const unsigned char* h0rd = lds + H0_OFF + (cur ^ 1) * 4096;
#pragma unroll
        for (int ks = 0; ks < 4; ks++) {
            h8 b = *(const h8*)(h0rd + ((c16 * 256 + ks * 64 + G4 * 16) ^ swzl));
#pragma unroll
            for (int j = 0; j < 4; j++) {
                h8 a = *(const h8*)(lds + WC0_OFF + (w * 64 + j * 16 + c16) * 256
                                    + ((ks * 64 + G4 * 16) ^ swzl));
                if (ks == 0) mfma_v0(acc0[j], a, b);
                else         mfma_v(acc0[j], a, b);
            }
        }
#pragma unroll
        for (int j = 0; j < 4; j++)     // builtin: compiler handles VALU(bx)->MFMA
            acc0[j] = __builtin_amdgcn_mfma_f32_16x16x16f16(ax16[j], bx, acc0[j], 0, 0, 0);

        // ---------------- layer 1 part A (h1_old-dependent), Wc1 from AGPRs
        const unsigned char* h1rd = lds + H1_OFF + (cur ^ 1) * 4096;
#pragma unroll
        for (int j = 0; j < 4; j++)
            acc1[j] = *(const f4*)(lds + BB_OFF + (w * 64 + j * 16 + G4 * 4) * 4);
#pragma unroll
        for (int ks = 0; ks < 4; ks++) {
            h8 b = *(const h8*)(h1rd + ((c16 * 256 + ks * 64 + G4 * 16) ^ swzl));
#pragma unroll
            for (int j = 0; j < 4; j++)
                mfma_a(acc1[j], wc1a[j][ks], b);
        }

        // ---------------- layer 0 epilogue -> h0[cur]  (acc0 ends on builtin:
        // compiler inserts the MFMA->VALU hazard waits)
        unsigned char* h0wr = lds + H0_OFF + cur * 4096;
        {
            h4 hv;
#pragma unroll
            for (int j = 0; j < 4; j++) {
                const float vi = sigm2_(acc0[j][0]);
                const float vf = sigm2_(acc0[j][1]);
                const float vg = tanh2_(acc0[j][2]);
                const float vo = sigm2_(acc0[j][3]);
                const float cn = vf * c0r[j] + vi * vg;
                c0r[j] = cn;
                hv[j] = (_Float16)(vo * tanhn_(cn));
            }
            *(h4*)(h0wr + ((c16 * 256 + w * 32 + G4 * 8) ^ swzl)) = hv;
        }

        __syncthreads();   // barrier A: h0_new visible

        // ---------------- layer 1 part B (h0_new-dependent)
        const unsigned char* h0n = lds + H0_OFF + cur * 4096;
#pragma unroll
        for (int ks = 0; ks < 4; ks++) {
            h8 b = *(const h8*)(h0n + ((c16 * 256 + ks * 64 + G4 * 16) ^ swzl));
#pragma unroll
            for (int j = 0; j < 4; j++) {
                if (ks == 3 && j == 3) mfma_a_last(acc1[j], wc1a[j][ks + 4], b);
                else                   mfma_a(acc1[j], wc1a[j][ks + 4], b);
            }
        }
        unsigned char* h1wr = lds + H1_OFF + cur * 4096;
        {
            h4 hv;
#pragma unroll
            for (int j = 0; j < 4; j++) {
                const float vi = sigm2_(acc1[j][0]);
                const float vf = sigm2_(acc1[j][1]);
                const float vg = tanh2_(acc1[j][2]);
                const float vo = sigm2_(acc1[j][3]);
                const float cn = vf * c1r[j] + vi * vg;
                c1r[j] = cn;
                hv[j] = (_Float16)(vo * tanhn_(cn));
            }
            *(h4*)(h1wr + ((c16 * 256 + w * 32 + G4 * 8) ^ swzl)) = hv;
        }

        __syncthreads();   // barrier B: cross-step ordering for the part-A hoist
        cur ^= 1;
    }

    // ---------------- head
    if (tid < 128) {
        const int r = tid >> 3, part = tid & 7;
        const unsigned char* h1f = lds + H1_OFF + 4096;   // t=63 wrote buffer 1
        const int rswz = (r & 7) << 4;
        float s0 = 0.f, s1 = 0.f, s2 = 0.f, s3 = 0.f, s4 = 0.f;
#pragma unroll
        for (int kk = 0; kk < 16; kk++) {
            const int k = part * 16 + kk;
            float a = (float)*(const _Float16*)(h1f + ((r * 256 + k * 2) ^ rswz));
            a = fmaxf(a, 0.f);
            s0 += a * Wd1[0 * H_ + k];
            s1 += a * Wd1[1 * H_ + k];
            s2 += a * Wd1[2 * H_ + k];
            s3 += a * Wd1[3 * H_ + k];
            s4 += a * Wd1[4 * H_ + k];
        }
#pragma unroll
        for (int m = 1; m < 8; m <<= 1) {
            s0 += __shfl_xor(s0, m);
            s1 += __shfl_xor(s1, m);
            s2 += __shfl_xor(s2, m);
            s3 += __shfl_xor(s3, m);
            s4 += __shfl_xor(s4, m);
        }
        if (part == 0) {
            float o = bd2[0];
            o += fmaxf(s0 + bd1[0], 0.f) * Wd2[0];
            o += fmaxf(s1 + bd1[1], 0.f) * Wd2[1];
            o += fmaxf(s2 + bd1[2], 0.f) * Wd2[2];
            o += fmaxf(s3 + bd1[3], 0.f) * Wd2[3];
            o += fmaxf(s4 + bd1[4], 0.f) * Wd2[4];
            out[rowbase + r] = o;
        }
    }
}

extern "C" void kernel_launch(void* const* d_in, const int* in_sizes, int n_in,
                              void* d_out, int out_size, void* d_ws, size_t ws_size,
                              hipStream_t stream)
{
    const float* x    = (const float*)d_in[0];
    const float* Wih0 = (const float*)d_in[1];
    const float* Whh0 = (const float*)d_in[2];
    const float* bih0 = (const float*)d_in[3];
    const float* bhh0 = (const float*)d_in[4];
    const float* Wih1 = (const float*)d_in[5];
    const float* Whh1 = (const float*)d_in[6];
    const float* bih1 = (const float*)d_in[7];
    const float* bhh1 = (const float*)d_in[8];
    const float* Wd1  = (const float*)d_in[9];
    const float* bd1  = (const float*)d_in[10];
    const float* Wd2  = (const float*)d_in[11];
    const float* bd2  = (const float*)d_in[12];

    lstm_fused_kernel<<<B_ / 16, 512, 0, stream>>>(
        x, Wih0, Whh0, bih0, bhh0, Wih1, Whh1, bih1, bhh1,
        Wd1, bd1, Wd2, bd2, (float*)d_out);
}

// Round 9
// 225.692 us; speedup vs baseline: 3.2425x; 3.2425x over previous
//
#include <hip/hip_runtime.h>

typedef _Float16 h8 __attribute__((ext_vector_type(8)));
typedef _Float16 h4 __attribute__((ext_vector_type(4)));
typedef float f4 __attribute__((ext_vector_type(4)));
typedef int i4v __attribute__((ext_vector_type(4)));

#define B_ 4096
#define T_ 64
#define I_ 8
#define H_ 128

// LDS layout (bytes). Total 149504 <= 163840.
#define WC0_OFF 0            // [512 packed-gates][128 k] fp16, 16-way XOR-swizzled
#define H0_OFF  131072       // 2 x [16 batch][128 u] fp16, swizzled
#define H1_OFF  139264       // 2 x [16][128]
#define BB_OFF  147456       // [512] f32 L1 bias, packed order
#define LDS_TOTAL 149504

#define LOG2E    1.4426950408889634f
#define TWOLOG2E 2.8853900817779268f

__device__ __forceinline__ float sigm2_(float v) {
    return __builtin_amdgcn_rcpf(1.f + exp2f(-v));
}
__device__ __forceinline__ float tanh2_(float v) {
    return 1.f - 2.f * __builtin_amdgcn_rcpf(exp2f(v) + 1.f);
}
__device__ __forceinline__ float tanhn_(float v) {
    return 1.f - 2.f * __builtin_amdgcn_rcpf(exp2f(TWOLOG2E * v) + 1.f);
}
__device__ __forceinline__ int gs_of(int p) {
    return (p & 3) * H_ + (p >> 6) * 16 + ((p >> 2) & 3) * 4 + ((p >> 4) & 3);
}
__device__ __forceinline__ float scl_(int q) { return (q == 2) ? TWOLOG2E : LOG2E; }

// ---- AGPR bank access. Allocator splits the unified 256-reg budget into
// 128 arch + 128 acc and memory-spills arch overflow (r3-r8 evidence:
// VGPR_Count pinned 128@512thr / 64@1024thr, WRITE_SIZE = threads x spill
// bytes). Park 24 of 32 Wc1 frags (96 regs) in the otherwise-idle AGPR half.
// Writes once at init; volatile reads per use (volatile blocks loop-invariant
// hoisting, which would recreate the arch pressure). MFMAs remain BUILTINS —
// r8 showed asm-volatile MFMAs destroy scheduling/regalloc (731 us).
__device__ __forceinline__ int ag_w(int v) {
    int r; asm volatile("v_accvgpr_write_b32 %0, %1" : "=a"(r) : "v"(v)); return r;
}
__device__ __forceinline__ int ag_r(int v) {
    int r; asm volatile("v_accvgpr_read_b32 %0, %1" : "=v"(r) : "a"(v)); return r;
}

// Packed gate order: p = w*64 + j*16 + G4*4 + q -> u = w*16 + G4*4 + j,
// original row gs = q*H + u. Thread (w,G4,c16) owns u = w*16+G4*4+{0..3} for
// batch c16 -> one ds_write_b64 per layer.
// Swizzle: every LDS access's row index == c16 (mod 16), rows are 256B =
// 16 x 16B slots -> XOR key (c16&15)<<4 makes all ds_read_b128 / ds_write_b64
// conflict-free (old 8-way key left ~4 extra cyc/op: 1.58e7 SQ_LDS_BANK_CONFLICT).
__global__ __launch_bounds__(512) void lstm_fused_kernel(
    const float* __restrict__ x,
    const float* __restrict__ Wih0, const float* __restrict__ Whh0,
    const float* __restrict__ bih0, const float* __restrict__ bhh0,
    const float* __restrict__ Wih1, const float* __restrict__ Whh1,
    const float* __restrict__ bih1, const float* __restrict__ bhh1,
    const float* __restrict__ Wd1, const float* __restrict__ bd1,
    const float* __restrict__ Wd2, const float* __restrict__ bd2,
    float* __restrict__ out)
{
    __shared__ __align__(16) unsigned char lds[LDS_TOTAL];
    const int tid = threadIdx.x;
    const int w   = tid >> 6;
    const int l   = tid & 63;
    const int c16 = l & 15;
    const int G4  = l >> 4;
    const int rowbase = blockIdx.x * 16;
    const int swzl = c16 << 4;          // 16-way key (l&15 == c16)

    // ---- init: Wc0 (packed order, prescaled, fp16, swizzled) -> LDS
    {
        const int p  = tid;
        const int gs = gs_of(p);
        const float sc = scl_(p & 3);
        const float* src = Whh0 + (size_t)gs * H_;
        const int swz = (p & 15) << 4;
        unsigned char* dst = lds + WC0_OFF + p * 256;
#pragma unroll
        for (int kb = 0; kb < 16; kb++) {
            float4 f0 = *(const float4*)(src + kb * 8);
            float4 f1 = *(const float4*)(src + kb * 8 + 4);
            h8 v;
            v[0]=(_Float16)(f0.x*sc); v[1]=(_Float16)(f0.y*sc);
            v[2]=(_Float16)(f0.z*sc); v[3]=(_Float16)(f0.w*sc);
            v[4]=(_Float16)(f1.x*sc); v[5]=(_Float16)(f1.y*sc);
            v[6]=(_Float16)(f1.z*sc); v[7]=(_Float16)(f1.w*sc);
            *(h8*)(dst + ((kb * 16) ^ swz)) = v;
        }
    }
    // zero the t=0 read buffers (index 1); L1 bias (packed) -> LDS
    {
        f4 z = {0.f, 0.f, 0.f, 0.f};
        if (tid < 256) *(f4*)(lds + H0_OFF + 4096 + tid * 16) = z;
        else           *(f4*)(lds + H1_OFF + 4096 + (tid - 256) * 16) = z;
        const int gs = gs_of(tid);
        ((float*)(lds + BB_OFF))[tid] = (bih1[gs] + bhh1[gs]) * scl_(tid & 3);
    }

    // ---- init: Wc1 A-frags: 24 -> AGPR bank, 8 -> arch VGPRs; ax frag
    int wag[96];                 // constant-indexed only (full unroll)
    h8 wc1v[4][2];               // ks = 6,7
    h4 ax16[4];
    {
        const float sc1 = scl_(c16 & 3);
#pragma unroll
        for (int j = 0; j < 4; j++) {
            const int gs = gs_of(w * 64 + j * 16 + c16);
#pragma unroll
            for (int ks = 0; ks < 8; ks++) {
                const int k0 = ks * 32 + G4 * 8;
                const float* src = (k0 < 128) ? (Whh1 + (size_t)gs * H_ + k0)
                                              : (Wih1 + (size_t)gs * H_ + (k0 - 128));
                float4 f0 = *(const float4*)src;
                float4 f1 = *(const float4*)(src + 4);
                h8 v;
                v[0]=(_Float16)(f0.x*sc1); v[1]=(_Float16)(f0.y*sc1);
                v[2]=(_Float16)(f0.z*sc1); v[3]=(_Float16)(f0.w*sc1);
                v[4]=(_Float16)(f1.x*sc1); v[5]=(_Float16)(f1.y*sc1);
                v[6]=(_Float16)(f1.z*sc1); v[7]=(_Float16)(f1.w*sc1);
                if (ks < 6) {
                    i4v iv = *(i4v*)&v;
                    wag[(j * 6 + ks) * 4 + 0] = ag_w(iv[0]);
                    wag[(j * 6 + ks) * 4 + 1] = ag_w(iv[1]);
                    wag[(j * 6 + ks) * 4 + 2] = ag_w(iv[2]);
                    wag[(j * 6 + ks) * 4 + 3] = ag_w(iv[3]);
                } else {
                    wc1v[j][ks - 6] = v;
                }
            }
            h4 a;
#pragma unroll
            for (int e = 0; e < 4; e++) {
                const int k = G4 * 4 + e;
                float val = 0.f;
                if (k < 8)       val = Wih0[(size_t)gs * I_ + k] * sc1;
                else if (k == 8) val = (bih0[gs] + bhh0[gs]) * sc1;
                a[e] = (_Float16)val;
            }
            ax16[j] = a;
        }
    }

    const float* xrow = x + (size_t)(rowbase + c16) * T_ * I_;
    float4 xf0 = *(const float4*)(xrow);
    float4 xf1 = *(const float4*)(xrow + 4);

    float c0r[4] = {0.f, 0.f, 0.f, 0.f};
    float c1r[4] = {0.f, 0.f, 0.f, 0.f};

    __syncthreads();

    int cur = 0;
    for (int t = 0; t < T_; t++) {
        // B-frag (K=16) for the x/bias chunk: k<8 = x_t, k=8 -> 1.0
        h4 bx;
        bx[0] = (_Float16)0.f; bx[1] = (_Float16)0.f;
        bx[2] = (_Float16)0.f; bx[3] = (_Float16)0.f;
        if (G4 == 0) {
            bx[0]=(_Float16)xf0.x; bx[1]=(_Float16)xf0.y;
            bx[2]=(_Float16)xf0.z; bx[3]=(_Float16)xf0.w;
        } else if (G4 == 1) {
            bx[0]=(_Float16)xf1.x; bx[1]=(_Float16)xf1.y;
            bx[2]=(_Float16)xf1.z; bx[3]=(_Float16)xf1.w;
        } else if (G4 == 2) {
            bx[0] = (_Float16)1.f;
        }
        if (t < T_ - 1) {
            xf0 = *(const float4*)(xrow + (t + 1) * 8);
            xf1 = *(const float4*)(xrow + (t + 1) * 8 + 4);
        }

        // ---------------- layer 0 MFMAs (h0_old + x/bias), Wc0 from LDS
        f4 acc0[4], acc1[4];
        {
            f4 z = {0.f, 0.f, 0.f, 0.f};
#pragma unroll
            for (int j = 0; j < 4; j++) acc0[j] = z;
        }
        const unsigned char* h0rd = lds + H0_OFF + (cur ^ 1) * 4096;
#pragma unroll
        for (int ks = 0; ks < 4; ks++) {
            h8 b = *(const h8*)(h0rd + ((c16 * 256 + ks * 64 + G4 * 16) ^ swzl));
#pragma unroll
            for (int j = 0; j < 4; j++) {
                h8 a = *(const h8*)(lds + WC0_OFF + (w * 64 + j * 16 + c16) * 256
                                    + ((ks * 64 + G4 * 16) ^ swzl));
                acc0[j] = __builtin_amdgcn_mfma_f32_16x16x32_f16(a, b, acc0[j], 0, 0, 0);
            }
        }
#pragma unroll
        for (int j = 0; j < 4; j++)
            acc0[j] = __builtin_amdgcn_mfma_f32_16x16x16f16(ax16[j], bx, acc0[j], 0, 0, 0);

        // ---------------- layer 1 part A (h1_old), Wc1 ks0..3 from AGPRs
        const unsigned char* h1rd = lds + H1_OFF + (cur ^ 1) * 4096;
#pragma unroll
        for (int j = 0; j < 4; j++)
            acc1[j] = *(const f4*)(lds + BB_OFF + (w * 64 + j * 16 + G4 * 4) * 4);
#pragma unroll
        for (int ks = 0; ks < 4; ks++) {
            h8 b = *(const h8*)(h1rd + ((c16 * 256 + ks * 64 + G4 * 16) ^ swzl));
#pragma unroll
            for (int j = 0; j < 4; j++) {
                i4v iv;
                iv[0] = ag_r(wag[(j * 6 + ks) * 4 + 0]);
                iv[1] = ag_r(wag[(j * 6 + ks) * 4 + 1]);
                iv[2] = ag_r(wag[(j * 6 + ks) * 4 + 2]);
                iv[3] = ag_r(wag[(j * 6 + ks) * 4 + 3]);
                h8 a = *(h8*)&iv;
                acc1[j] = __builtin_amdgcn_mfma_f32_16x16x32_f16(a, b, acc1[j], 0, 0, 0);
            }
        }

        // ---------------- layer 0 epilogue -> h0[cur]
        unsigned char* h0wr = lds + H0_OFF + cur * 4096;
        {
            h4 hv;
#pragma unroll
            for (int j = 0; j < 4; j++) {
                const float vi = sigm2_(acc0[j][0]);
                const float vf = sigm2_(acc0[j][1]);
                const float vg = tanh2_(acc0[j][2]);
                const float vo = sigm2_(acc0[j][3]);
                const float cn = vf * c0r[j] + vi * vg;
                c0r[j] = cn;
                hv[j] = (_Float16)(vo * tanhn_(cn));
            }
            *(h4*)(h0wr + ((c16 * 256 + w * 32 + G4 * 8) ^ swzl)) = hv;
        }

        __syncthreads();   // barrier A: h0_new visible

        // ---------------- layer 1 part B (h0_new), ks4,5 AGPR; ks6,7 VGPR
        const unsigned char* h0n = lds + H0_OFF + cur * 4096;
#pragma unroll
        for (int ks = 0; ks < 4; ks++) {
            h8 b = *(const h8*)(h0n + ((c16 * 256 + ks * 64 + G4 * 16) ^ swzl));
#pragma unroll
            for (int j = 0; j < 4; j++) {
                h8 a;
                if (ks < 2) {
                    i4v iv;
                    iv[0] = ag_r(wag[(j * 6 + 4 + ks) * 4 + 0]);
                    iv[1] = ag_r(wag[(j * 6 + 4 + ks) * 4 + 1]);
                    iv[2] = ag_r(wag[(j * 6 + 4 + ks) * 4 + 2]);
                    iv[3] = ag_r(wag[(j * 6 + 4 + ks) * 4 + 3]);
                    a = *(h8*)&iv;
                } else {
                    a = wc1v[j][ks - 2];
                }
                acc1[j] = __builtin_amdgcn_mfma_f32_16x16x32_f16(a, b, acc1[j], 0, 0, 0);
            }
        }
        unsigned char* h1wr = lds + H1_OFF + cur * 4096;
        {
            h4 hv;
#pragma unroll
            for (int j = 0; j < 4; j++) {
                const float vi = sigm2_(acc1[j][0]);
                const float vf = sigm2_(acc1[j][1]);
                const float vg = tanh2_(acc1[j][2]);
                const float vo = sigm2_(acc1[j][3]);
                const float cn = vf * c1r[j] + vi * vg;
                c1r[j] = cn;
                hv[j] = (_Float16)(vo * tanhn_(cn));
            }
            *(h4*)(h1wr + ((c16 * 256 + w * 32 + G4 * 8) ^ swzl)) = hv;
        }

        __syncthreads();   // barrier B: cross-step ordering for the part-A hoist
        cur ^= 1;
    }

    // ---------------- head
    if (tid < 128) {
        const int r = tid >> 3, part = tid & 7;
        const unsigned char* h1f = lds + H1_OFF + 4096;   // t=63 wrote buffer 1
        const int rswz = r << 4;
        float s0 = 0.f, s1 = 0.f, s2 = 0.f, s3 = 0.f, s4 = 0.f;
#pragma unroll
        for (int kk = 0; kk < 16; kk++) {
            const int k = part * 16 + kk;
            float a = (float)*(const _Float16*)(h1f + ((r * 256 + k * 2) ^ rswz));
            a = fmaxf(a, 0.f);
            s0 += a * Wd1[0 * H_ + k];
            s1 += a * Wd1[1 * H_ + k];
            s2 += a * Wd1[2 * H_ + k];
            s3 += a * Wd1[3 * H_ + k];
            s4 += a * Wd1[4 * H_ + k];
        }
#pragma unroll
        for (int m = 1; m < 8; m <<= 1) {
            s0 += __shfl_xor(s0, m);
            s1 += __shfl_xor(s1, m);
            s2 += __shfl_xor(s2, m);
            s3 += __shfl_xor(s3, m);
            s4 += __shfl_xor(s4, m);
        }
        if (part == 0) {
            float o = bd2[0];
            o += fmaxf(s0 + bd1[0], 0.f) * Wd2[0];
            o += fmaxf(s1 + bd1[1], 0.f) * Wd2[1];
            o += fmaxf(s2 + bd1[2], 0.f) * Wd2[2];
            o += fmaxf(s3 + bd1[3], 0.f) * Wd2[3];
            o += fmaxf(s4 + bd1[4], 0.f) * Wd2[4];
            out[rowbase + r] = o;
        }
    }
}

extern "C" void kernel_launch(void* const* d_in, const int* in_sizes, int n_in,
                              void* d_out, int out_size, void* d_ws, size_t ws_size,
                              hipStream_t stream)
{
    const float* x    = (const float*)d_in[0];
    const float* Wih0 = (const float*)d_in[1];
    const float* Whh0 = (const float*)d_in[2];
    const float* bih0 = (const float*)d_in[3];
    const float* bhh0 = (const float*)d_in[4];
    const float* Wih1 = (const float*)d_in[5];
    const float* Whh1 = (const float*)d_in[6];
    const float* bih1 = (const float*)d_in[7];
    const float* bhh1 = (const float*)d_in[8];
    const float* Wd1  = (const float*)d_in[9];
    const float* bd1  = (const float*)d_in[10];
    const float* Wd2  = (const float*)d_in[11];
    const float* bd2  = (const float*)d_in[12];

    lstm_fused_kernel<<<B_ / 16, 512, 0, stream>>>(
        x, Wih0, Whh0, bih0, bhh0, Wih1, Whh1, bih1, bhh1,
        Wd1, bd1, Wd2, bd2, (float*)d_out);
}